// Round 2
// baseline (271.373 us; speedup 1.0000x reference)
//
#include <hip/hip_runtime.h>

typedef __attribute__((ext_vector_type(4))) float f32x4;
typedef __attribute__((ext_vector_type(8))) short s16x8;
typedef __attribute__((ext_vector_type(8))) unsigned short u16x8;
typedef __attribute__((address_space(1))) unsigned int g_uint;
typedef __attribute__((address_space(3))) unsigned int lds_uint;

#define T_LEN 2048
#define ENC_D 1024
#define ATT_D 512
#define CONV_C 10

static __device__ __forceinline__ unsigned short f2bf(float f) {
  unsigned int u = __float_as_uint(f);
  u += 0x7FFFu + ((u >> 16) & 1u);
  return (unsigned short)(u >> 16);
}

static __device__ __forceinline__ void gload16(const void* g, void* l) {
  __builtin_amdgcn_global_load_lds((const g_uint*)g, (lds_uint*)l, 16, 0, 0);
}

// ---------------- K0a: Wt[a][k] = bf16(W_enc[k][a]) ----------------
__global__ void k_wt(const float* __restrict__ W, unsigned short* __restrict__ Wt) {
  __shared__ float tile[64][65];
  int k0 = blockIdx.x * 64, a0 = blockIdx.y * 64;
  int tid = threadIdx.x;
  int r = tid >> 2, cg = tid & 3;
  #pragma unroll
  for (int i = 0; i < 4; ++i) {
    f32x4 v = *reinterpret_cast<const f32x4*>(&W[(size_t)(k0 + r) * ATT_D + a0 + cg * 16 + i * 4]);
    tile[r][cg * 16 + i * 4 + 0] = v[0];
    tile[r][cg * 16 + i * 4 + 1] = v[1];
    tile[r][cg * 16 + i * 4 + 2] = v[2];
    tile[r][cg * 16 + i * 4 + 3] = v[3];
  }
  __syncthreads();
  int r2 = tid >> 2, kg = tid & 3;
  u16x8 o0, o1;
  #pragma unroll
  for (int j = 0; j < 8; ++j) o0[j] = f2bf(tile[kg * 16 + j][r2]);
  #pragma unroll
  for (int j = 0; j < 8; ++j) o1[j] = f2bf(tile[kg * 16 + 8 + j][r2]);
  unsigned short* dst = &Wt[(size_t)(a0 + r2) * ENC_D + k0 + kg * 16];
  *reinterpret_cast<u16x8*>(dst) = o0;
  *reinterpret_cast<u16x8*>(dst + 8) = o1;
}

// ---------------- K0b: f_out[n][c][t] = conv129(ali_prev) + F_b ----------------
__global__ void k_conv(const float* __restrict__ ali, const float* __restrict__ Fw,
                       const float* __restrict__ Fb, float* __restrict__ fout) {
  int b = blockIdx.x;
  int tb = b & 7, nc = b >> 3;
  int c = nc % CONV_C, n = nc / CONV_C;
  __shared__ float sa[384];
  __shared__ float sw[129];
  int tid = threadIdx.x;
  int t0 = tb * 256;
  for (int i = tid; i < 384; i += 256) {
    int t = t0 - 64 + i;
    sa[i] = (t >= 0 && t < T_LEN) ? ali[n * T_LEN + t] : 0.f;
  }
  if (tid < 129) sw[tid] = Fw[c * 129 + tid];
  __syncthreads();
  float acc = Fb[c];
  #pragma unroll 8
  for (int k = 0; k < 129; ++k) acc += sw[k] * sa[tid + k];
  fout[(size_t)(n * CONV_C + c) * T_LEN + t0 + tid] = acc;
}

// ---------------- K0c: dec_ws[n][a] = dec_prev[n]@W_dec[:,a] + b_enc[a] ----------------
__global__ void k_dec(const float* __restrict__ dec_prev, const float* __restrict__ Wd,
                      const float* __restrict__ benc, float* __restrict__ dec_ws) {
  int b = blockIdx.x;
  int n = b >> 1, half = b & 1;
  int a = half * 256 + threadIdx.x;
  __shared__ float sd[1024];
  for (int i = threadIdx.x; i < 1024; i += 256) sd[i] = dec_prev[n * 1024 + i];
  __syncthreads();
  float acc = benc[a];
  #pragma unroll 8
  for (int d = 0; d < 1024; ++d) acc += sd[d] * Wd[(size_t)d * ATT_D + a];
  dec_ws[n * ATT_D + a] = acc;
}

// ---------------- K1: fused score GEMM (BM=128, BN=256-half, BK=32) ----------------
__global__ __launch_bounds__(256, 2) void k_score(
    const float* __restrict__ enc, const unsigned short* __restrict__ Wt,
    const float* __restrict__ fout, const float* __restrict__ dec_ws,
    const float* __restrict__ W_att, const float* __restrict__ w_vec,
    float* __restrict__ score_ws) {
  __shared__ __align__(16) char smem[49152];
  short* A0 = (short*)(smem);             // [128][32] bf16 = 8192 B
  short* A1 = (short*)(smem + 8192);
  short* B0 = (short*)(smem + 16384);     // [256][32] bf16 = 16384 B
  short* B1 = (short*)(smem + 32768);

  int bid = blockIdx.x;                   // nwg = 1024 (512 mt x 2 h)
  int xcd = bid & 7, idx = bid >> 3;      // bijective: 1024 % 8 == 0
  int mt = xcd * 64 + (idx >> 1);         // pair h-blocks of same mt on one XCD
  int h = idx & 1;

  int tid = threadIdx.x;
  int w = tid >> 6, lane = tid & 63;
  int l15 = lane & 15, q = lane >> 4;
  int wm = w >> 1, wn = w & 1;            // wave tile 64x128

  const float* Ab = enc + (size_t)mt * (128 * ENC_D);
  const unsigned short* Bb = Wt + (size_t)h * (256 * ENC_D);

  // A staging: thread -> row rA = tid>>1, 16 floats at col hA*16
  int rA = tid >> 1, hA = tid & 1;
  const float* Agp = Ab + (size_t)rA * ENC_D + hA * 16;
  // B staging: 4 x global_load_lds(16B); instr i: row i*64 + (tid>>2), chunk tid&3
  int rB = tid >> 2, kcB = tid & 3;
  const unsigned short* Bgp = Bb + (size_t)rB * ENC_D + kcB * 8;
  int ldsB = tid * 16;                    // byte offset of this lane's 16B, + i*4096

  f32x4 acc[4][8];
  #pragma unroll
  for (int m = 0; m < 4; ++m)
    #pragma unroll
    for (int nf = 0; nf < 8; ++nf)
      acc[m][nf] = (f32x4){0.f, 0.f, 0.f, 0.f};

  f32x4 ar[4];
  auto loadA = [&](int kt) {
    const float* p = Agp + kt * 32;
    ar[0] = *reinterpret_cast<const f32x4*>(p);
    ar[1] = *reinterpret_cast<const f32x4*>(p + 4);
    ar[2] = *reinterpret_cast<const f32x4*>(p + 8);
    ar[3] = *reinterpret_cast<const f32x4*>(p + 12);
  };
  auto writeA = [&](short* A) {
    u16x8 t0v, t1v;
    #pragma unroll
    for (int j = 0; j < 4; ++j) { t0v[j] = f2bf(ar[0][j]); t0v[4 + j] = f2bf(ar[1][j]); }
    #pragma unroll
    for (int j = 0; j < 4; ++j) { t1v[j] = f2bf(ar[2][j]); t1v[4 + j] = f2bf(ar[3][j]); }
    short* dst = &A[rA * 32 + hA * 16];
    *reinterpret_cast<u16x8*>(dst) = t0v;
    *reinterpret_cast<u16x8*>(dst + 8) = t1v;
  };
  auto loadB = [&](int kt, short* B) {
    const unsigned short* src = Bgp + kt * 32;
    char* dst = (char*)B + ldsB;
    #pragma unroll
    for (int i = 0; i < 4; ++i)
      gload16(src + (size_t)i * (64 * ENC_D), dst + i * 4096);
  };
  auto compute = [&](const short* A, const short* B) {
    s16x8 af[4];
    #pragma unroll
    for (int m = 0; m < 4; ++m)
      af[m] = *reinterpret_cast<const s16x8*>(&A[(wm * 64 + m * 16 + l15) * 32 + q * 8]);
    #pragma unroll
    for (int half = 0; half < 2; ++half) {
      s16x8 bfr[4];
      #pragma unroll
      for (int i = 0; i < 4; ++i)
        bfr[i] = *reinterpret_cast<const s16x8*>(&B[(wn * 128 + (half * 4 + i) * 16 + l15) * 32 + q * 8]);
      #pragma unroll
      for (int m = 0; m < 4; ++m)
        #pragma unroll
        for (int i = 0; i < 4; ++i)
          acc[m][half * 4 + i] = __builtin_amdgcn_mfma_f32_16x16x32_bf16(af[m], bfr[i], acc[m][half * 4 + i], 0, 0, 0);
    }
  };

  loadA(0);
  loadB(0, B0);
  writeA(A0);
  __syncthreads();

  for (int kt = 0; kt < 32; kt += 2) {
    loadA(kt + 1);
    loadB(kt + 1, B1);
    compute(A0, B0);
    writeA(A1);
    __syncthreads();
    if (kt + 2 < 32) {
      loadA(kt + 2);
      loadB(kt + 2, B0);
    }
    compute(A1, B1);
    if (kt + 2 < 32) writeA(A0);
    __syncthreads();
  }

  // ---- epilogue: att mix + dec + tanh + dot(w) + row-reduce ----
  float* f_lds = (float*)smem;               // [10][128] = 5120
  float* attw  = (float*)(smem + 5120);      // [256][10] = 10240
  float* d_lds = (float*)(smem + 15360);     // [256]
  float* w_lds = (float*)(smem + 16384);     // [256]
  float* red   = (float*)(smem + 17408);     // [4][64]

  int n = mt >> 4;
  int t0 = (mt & 15) * 128;

  for (int i = tid; i < 1280; i += 256) {
    int c = i >> 7, tt = i & 127;
    f_lds[c * 128 + tt] = fout[(size_t)(n * CONV_C + c) * T_LEN + t0 + tt];
  }
  for (int i = tid; i < 2560; i += 256) attw[i] = W_att[h * 2560 + i];
  d_lds[tid] = dec_ws[n * ATT_D + h * 256 + tid];
  w_lds[tid] = w_vec[h * 256 + tid];
  __syncthreads();

  #pragma unroll
  for (int m = 0; m < 4; ++m) {
    #pragma unroll
    for (int j = 0; j < 4; ++j) {
      int tt = wm * 64 + m * 16 + q * 4 + j;
      float s = 0.f;
      #pragma unroll
      for (int nf = 0; nf < 8; ++nf) {
        int cl = wn * 128 + nf * 16 + l15;
        float att = 0.f;
        #pragma unroll
        for (int c = 0; c < CONV_C; ++c) att += f_lds[c * 128 + tt] * attw[cl * CONV_C + c];
        float x = acc[m][nf][j] + d_lds[cl] + att;
        float e = __expf(2.f * x);
        float th = 1.f - 2.f / (e + 1.f);
        s += w_lds[cl] * th;
      }
      float v = s;
      v += __shfl_xor(v, 1);
      v += __shfl_xor(v, 2);
      v += __shfl_xor(v, 4);
      v += __shfl_xor(v, 8);
      if (l15 == 0) red[w * 64 + m * 16 + q * 4 + j] = v;
    }
  }
  __syncthreads();
  if (tid < 128) {
    int wm2 = tid >> 6, rr = tid & 63;
    float s = red[(wm2 * 2 + 0) * 64 + rr] + red[(wm2 * 2 + 1) * 64 + rr];
    score_ws[(size_t)h * 65536 + (size_t)mt * 128 + tid] = s;
  }
}

// ---------------- K2: masked softmax over T per row ----------------
__global__ void k_softmax(const float* __restrict__ score_ws, const int* __restrict__ enc_len,
                          float* __restrict__ ali_out) {
  __shared__ float wmx[4], wsum[4];
  int n = blockIdx.x, tid = threadIdx.x;
  int len = enc_len[n];
  int w = tid >> 6, lane = tid & 63;
  float s[8], e[8];
  float mx = -1e30f;
  #pragma unroll
  for (int i = 0; i < 8; ++i) {
    int t = i * 256 + tid;
    float v = score_ws[n * T_LEN + t] + score_ws[65536 + n * T_LEN + t];
    s[i] = v;
    if (t < len) mx = fmaxf(mx, v);
  }
  #pragma unroll
  for (int off = 32; off; off >>= 1) mx = fmaxf(mx, __shfl_xor(mx, off));
  if (lane == 0) wmx[w] = mx;
  __syncthreads();
  mx = fmaxf(fmaxf(wmx[0], wmx[1]), fmaxf(wmx[2], wmx[3]));
  float sum = 0.f;
  #pragma unroll
  for (int i = 0; i < 8; ++i) {
    int t = i * 256 + tid;
    float v = (t < len) ? __expf(s[i] - mx) : 0.f;
    e[i] = v;
    sum += v;
  }
  #pragma unroll
  for (int off = 32; off; off >>= 1) sum += __shfl_xor(sum, off);
  if (lane == 0) wsum[w] = sum;
  __syncthreads();
  sum = wsum[0] + wsum[1] + wsum[2] + wsum[3];
  float inv = 1.f / sum;
  #pragma unroll
  for (int i = 0; i < 8; ++i) ali_out[n * T_LEN + i * 256 + tid] = e[i] * inv;
}

// ---------------- K3: ctx partials over T-chunks ----------------
__global__ void k_ctx(const float* __restrict__ ali, const float* __restrict__ enc,
                      float* __restrict__ part) {
  int b = blockIdx.x;                   // n*32 + tc
  int n = b >> 5, tc = b & 31;
  int tid = threadIdx.x;
  f32x4 acc = (f32x4){0.f, 0.f, 0.f, 0.f};
  const float* ep = enc + (size_t)(n * T_LEN + tc * 64) * ENC_D + tid * 4;
  const float* ap = ali + n * T_LEN + tc * 64;
  #pragma unroll 4
  for (int i = 0; i < 64; ++i) {
    float a = ap[i];
    f32x4 ev = *reinterpret_cast<const f32x4*>(ep + (size_t)i * ENC_D);
    acc += ev * a;
  }
  *reinterpret_cast<f32x4*>(&part[(size_t)b * ENC_D + tid * 4]) = acc;
}

// ---------------- K4: reduce ctx partials ----------------
__global__ void k_ctx_red(const float* __restrict__ part, float* __restrict__ ctx_out) {
  int g = blockIdx.x * 256 + threadIdx.x;
  int n = g >> 10, d = g & 1023;
  float s = 0.f;
  #pragma unroll 8
  for (int tc = 0; tc < 32; ++tc) s += part[(size_t)(n * 32 + tc) * ENC_D + d];
  ctx_out[g] = s;
}

extern "C" void kernel_launch(void* const* d_in, const int* in_sizes, int n_in,
                              void* d_out, int out_size, void* d_ws, size_t ws_size,
                              hipStream_t stream) {
  const float* enc      = (const float*)d_in[0];
  const int*   enc_len  = (const int*)d_in[1];
  const float* dec_prev = (const float*)d_in[2];
  const float* ali_prev = (const float*)d_in[3];
  const float* W_enc    = (const float*)d_in[4];
  const float* b_enc    = (const float*)d_in[5];
  const float* W_dec    = (const float*)d_in[6];
  const float* F_w      = (const float*)d_in[7];
  const float* F_b      = (const float*)d_in[8];
  const float* W_att    = (const float*)d_in[9];
  const float* w_vec    = (const float*)d_in[10];
  float* out = (float*)d_out;

  char* ws = (char*)d_ws;
  unsigned short* Wt = (unsigned short*)ws;        // 1,048,576 B
  float* fout   = (float*)(ws + 1048576);          // 2,621,440 B
  float* dec_ws = (float*)(ws + 3670016);          //    65,536 B
  float* score  = (float*)(ws + 3735552);          //   524,288 B
  float* part   = (float*)(ws + 4259840);          // 4,194,304 B

  dim3 blk(256);
  hipLaunchKernelGGL(k_wt, dim3(16, 8), blk, 0, stream, W_enc, Wt);
  hipLaunchKernelGGL(k_conv, dim3(2560), blk, 0, stream, ali_prev, F_w, F_b, fout);
  hipLaunchKernelGGL(k_dec, dim3(64), blk, 0, stream, dec_prev, W_dec, b_enc, dec_ws);
  hipLaunchKernelGGL(k_score, dim3(1024), blk, 0, stream, enc, Wt, fout, dec_ws, W_att, w_vec, score);
  hipLaunchKernelGGL(k_softmax, dim3(32), blk, 0, stream, score, enc_len, out);
  hipLaunchKernelGGL(k_ctx, dim3(1024), blk, 0, stream, out, enc, part);
  hipLaunchKernelGGL(k_ctx_red, dim3(128), blk, 0, stream, part, out + 65536);
}

// Round 3
// 263.143 us; speedup vs baseline: 1.0313x; 1.0313x over previous
//
#include <hip/hip_runtime.h>

typedef __attribute__((ext_vector_type(4))) float f32x4;
typedef __attribute__((ext_vector_type(8))) short s16x8;
typedef __attribute__((ext_vector_type(4))) unsigned short u16x4;
typedef __attribute__((ext_vector_type(8))) unsigned short u16x8;
typedef __attribute__((address_space(1))) unsigned int g_uint;
typedef __attribute__((address_space(3))) unsigned int lds_uint;

#define T_LEN 2048
#define ENC_D 1024
#define ATT_D 512
#define CONV_C 10

static __device__ __forceinline__ unsigned short f2bf(float f) {
  unsigned int u = __float_as_uint(f);
  u += 0x7FFFu + ((u >> 16) & 1u);
  return (unsigned short)(u >> 16);
}

static __device__ __forceinline__ void gload16(const void* g, void* l) {
  __builtin_amdgcn_global_load_lds((const g_uint*)g, (lds_uint*)l, 16, 0, 0);
}

// ---------------- K0a: Wt2 tiled: tile(h,kt)[a_local 256][k_local 32] bf16 ----------------
__global__ void k_wt(const float* __restrict__ W, unsigned short* __restrict__ Wt2) {
  __shared__ float tile[64][65];
  int k0 = blockIdx.x * 64, a0 = blockIdx.y * 64;
  int tid = threadIdx.x;
  int r = tid >> 2, cg = tid & 3;
  #pragma unroll
  for (int i = 0; i < 4; ++i) {
    f32x4 v = *reinterpret_cast<const f32x4*>(&W[(size_t)(k0 + r) * ATT_D + a0 + cg * 16 + i * 4]);
    tile[r][cg * 16 + i * 4 + 0] = v[0];
    tile[r][cg * 16 + i * 4 + 1] = v[1];
    tile[r][cg * 16 + i * 4 + 2] = v[2];
    tile[r][cg * 16 + i * 4 + 3] = v[3];
  }
  __syncthreads();
  int r2 = tid >> 2, kg = tid & 3;
  u16x8 o0, o1;
  #pragma unroll
  for (int j = 0; j < 8; ++j) o0[j] = f2bf(tile[kg * 16 + j][r2]);
  #pragma unroll
  for (int j = 0; j < 8; ++j) o1[j] = f2bf(tile[kg * 16 + 8 + j][r2]);
  int a = a0 + r2;            // 0..511
  int k = k0 + kg * 16;       // 0..1023, 16-aligned (within one 32-wide kt)
  size_t base = ((size_t)(a >> 8) * 32 + (k >> 5)) * 8192 + (size_t)(a & 255) * 32 + (k & 31);
  *reinterpret_cast<u16x8*>(&Wt2[base]) = o0;
  *reinterpret_cast<u16x8*>(&Wt2[base + 8]) = o1;
}

// ---------------- K0b: f_out[n][c][t] = conv129(ali_prev) + F_b ----------------
__global__ void k_conv(const float* __restrict__ ali, const float* __restrict__ Fw,
                       const float* __restrict__ Fb, float* __restrict__ fout) {
  int b = blockIdx.x;
  int tb = b & 7, nc = b >> 3;
  int c = nc % CONV_C, n = nc / CONV_C;
  __shared__ float sa[384];
  __shared__ float sw[129];
  int tid = threadIdx.x;
  int t0 = tb * 256;
  for (int i = tid; i < 384; i += 256) {
    int t = t0 - 64 + i;
    sa[i] = (t >= 0 && t < T_LEN) ? ali[n * T_LEN + t] : 0.f;
  }
  if (tid < 129) sw[tid] = Fw[c * 129 + tid];
  __syncthreads();
  float acc = Fb[c];
  #pragma unroll 8
  for (int k = 0; k < 129; ++k) acc += sw[k] * sa[tid + k];
  fout[(size_t)(n * CONV_C + c) * T_LEN + t0 + tid] = acc;
}

// ---------------- K0c: dec_ws[n][a] = dec_prev[n]@W_dec[:,a] + b_enc[a] ----------------
__global__ void k_dec(const float* __restrict__ dec_prev, const float* __restrict__ Wd,
                      const float* __restrict__ benc, float* __restrict__ dec_ws) {
  int b = blockIdx.x;
  int n = b >> 1, half = b & 1;
  int a = half * 256 + threadIdx.x;
  __shared__ float sd[1024];
  for (int i = threadIdx.x; i < 1024; i += 256) sd[i] = dec_prev[n * 1024 + i];
  __syncthreads();
  float acc = benc[a];
  #pragma unroll 8
  for (int d = 0; d < 1024; ++d) acc += sd[d] * Wd[(size_t)d * ATT_D + a];
  dec_ws[n * ATT_D + a] = acc;
}

// ---------------- K1: fused score GEMM (BM=128, BN=256-half, BK=32) ----------------
// Single barrier per K-step; B via contiguous global_load_lds from tiled Wt2;
// A via coalesced 128B-row reg-staging + in-register bf16 convert + b64 LDS write.
__global__ __launch_bounds__(256, 2) void k_score(
    const float* __restrict__ enc, const unsigned short* __restrict__ Wt2,
    const float* __restrict__ fout, const float* __restrict__ dec_ws,
    const float* __restrict__ W_att, const float* __restrict__ w_vec,
    float* __restrict__ score_ws) {
  __shared__ __align__(16) char smem[49152];
  short* B0 = (short*)(smem);             // [256][32] bf16 = 16384 B
  short* B1 = (short*)(smem + 16384);
  short* A0 = (short*)(smem + 32768);     // [128][32] bf16 = 8192 B
  short* A1 = (short*)(smem + 40960);

  int bid = blockIdx.x;                   // nwg = 1024 (512 mt x 2 h)
  int xcd = bid & 7, idx = bid >> 3;      // bijective: 1024 % 8 == 0
  int mt = xcd * 64 + (idx >> 1);         // pair h-blocks of same mt on one XCD
  int h = idx & 1;

  int tid = threadIdx.x;
  int w = tid >> 6, lane = tid & 63;
  int l15 = lane & 15, q = lane >> 4;
  int wm = w >> 1, wn = w & 1;            // wave tile 64x128

  const float* Ab = enc + (size_t)mt * (128 * ENC_D);

  int rA = tid >> 3, cA = (tid & 7) * 4;  // A: row j*32+rA, 16B chunk cA

  f32x4 acc[4][8];
  #pragma unroll
  for (int m = 0; m < 4; ++m)
    #pragma unroll
    for (int nf = 0; nf < 8; ++nf)
      acc[m][nf] = (f32x4){0.f, 0.f, 0.f, 0.f};

  f32x4 rv[4];
  auto loadA = [&](int kt) {
    #pragma unroll
    for (int j = 0; j < 4; ++j)
      rv[j] = *reinterpret_cast<const f32x4*>(Ab + (size_t)(j * 32 + rA) * ENC_D + kt * 32 + cA);
  };
  auto writeA = [&](short* A) {
    #pragma unroll
    for (int j = 0; j < 4; ++j) {
      u16x4 v;
      v[0] = f2bf(rv[j][0]); v[1] = f2bf(rv[j][1]);
      v[2] = f2bf(rv[j][2]); v[3] = f2bf(rv[j][3]);
      *reinterpret_cast<u16x4*>(&A[(j * 32 + rA) * 32 + cA]) = v;
    }
  };
  auto loadB = [&](int kt, short* B) {
    const unsigned short* src = Wt2 + ((size_t)h * 32 + kt) * 8192 + tid * 8;
    char* dst = (char*)B + tid * 16;
    #pragma unroll
    for (int i = 0; i < 4; ++i)
      gload16(src + i * 2048, dst + i * 4096);
  };
  auto compute = [&](const short* A, const short* B) {
    s16x8 af[4];
    #pragma unroll
    for (int m = 0; m < 4; ++m)
      af[m] = *reinterpret_cast<const s16x8*>(&A[(wm * 64 + m * 16 + l15) * 32 + q * 8]);
    #pragma unroll
    for (int half = 0; half < 2; ++half) {
      s16x8 bfr[4];
      #pragma unroll
      for (int i = 0; i < 4; ++i)
        bfr[i] = *reinterpret_cast<const s16x8*>(&B[(wn * 128 + (half * 4 + i) * 16 + l15) * 32 + q * 8]);
      #pragma unroll
      for (int m = 0; m < 4; ++m)
        #pragma unroll
        for (int i = 0; i < 4; ++i)
          acc[m][half * 4 + i] = __builtin_amdgcn_mfma_f32_16x16x32_bf16(af[m], bfr[i], acc[m][half * 4 + i], 0, 0, 0);
    }
  };

  // prologue: stage kt=0 into buffer 0
  loadB(0, B0);
  loadA(0);
  writeA(A0);

  for (int kt = 0; kt < 32; kt += 2) {
    __syncthreads();                       // buf0 for kt ready (vmcnt+lgkm drained)
    loadB(kt + 1, B1);                     // async stage kt+1
    loadA(kt + 1);
    compute(A0, B0);
    writeA(A1);                            // convert after MFMAs (A-load latency covered)
    __syncthreads();                       // buf1 for kt+1 ready
    if (kt + 2 < 32) {
      loadB(kt + 2, B0);
      loadA(kt + 2);
    }
    compute(A1, B1);
    if (kt + 2 < 32) writeA(A0);
  }
  __syncthreads();

  // ---- epilogue: att mix + dec + tanh + dot(w) + row-reduce ----
  float* f_lds = (float*)smem;               // [10][128] = 5120
  float* attw  = (float*)(smem + 5120);      // [256][10] = 10240
  float* d_lds = (float*)(smem + 15360);     // [256]
  float* w_lds = (float*)(smem + 16384);     // [256]
  float* red   = (float*)(smem + 17408);     // [4][64]

  int n = mt >> 4;
  int t0 = (mt & 15) * 128;

  for (int i = tid; i < 1280; i += 256) {
    int c = i >> 7, tt = i & 127;
    f_lds[c * 128 + tt] = fout[(size_t)(n * CONV_C + c) * T_LEN + t0 + tt];
  }
  for (int i = tid; i < 2560; i += 256) attw[i] = W_att[h * 2560 + i];
  d_lds[tid] = dec_ws[n * ATT_D + h * 256 + tid];
  w_lds[tid] = w_vec[h * 256 + tid];
  __syncthreads();

  #pragma unroll
  for (int m = 0; m < 4; ++m) {
    #pragma unroll
    for (int j = 0; j < 4; ++j) {
      int tt = wm * 64 + m * 16 + q * 4 + j;
      float s = 0.f;
      #pragma unroll
      for (int nf = 0; nf < 8; ++nf) {
        int cl = wn * 128 + nf * 16 + l15;
        float att = 0.f;
        #pragma unroll
        for (int c = 0; c < CONV_C; ++c) att += f_lds[c * 128 + tt] * attw[cl * CONV_C + c];
        float x = acc[m][nf][j] + d_lds[cl] + att;
        float e = __expf(2.f * x);
        float th = 1.f - 2.f / (e + 1.f);
        s += w_lds[cl] * th;
      }
      float v = s;
      v += __shfl_xor(v, 1);
      v += __shfl_xor(v, 2);
      v += __shfl_xor(v, 4);
      v += __shfl_xor(v, 8);
      if (l15 == 0) red[w * 64 + m * 16 + q * 4 + j] = v;
    }
  }
  __syncthreads();
  if (tid < 128) {
    int wm2 = tid >> 6, rr = tid & 63;
    float s = red[(wm2 * 2 + 0) * 64 + rr] + red[(wm2 * 2 + 1) * 64 + rr];
    score_ws[(size_t)h * 65536 + (size_t)mt * 128 + tid] = s;
  }
}

// ---------------- K2: masked softmax over T per row ----------------
__global__ void k_softmax(const float* __restrict__ score_ws, const int* __restrict__ enc_len,
                          float* __restrict__ ali_out) {
  __shared__ float wmx[4], wsum[4];
  int n = blockIdx.x, tid = threadIdx.x;
  int len = enc_len[n];
  int w = tid >> 6, lane = tid & 63;
  float s[8], e[8];
  float mx = -1e30f;
  #pragma unroll
  for (int i = 0; i < 8; ++i) {
    int t = i * 256 + tid;
    float v = score_ws[n * T_LEN + t] + score_ws[65536 + n * T_LEN + t];
    s[i] = v;
    if (t < len) mx = fmaxf(mx, v);
  }
  #pragma unroll
  for (int off = 32; off; off >>= 1) mx = fmaxf(mx, __shfl_xor(mx, off));
  if (lane == 0) wmx[w] = mx;
  __syncthreads();
  mx = fmaxf(fmaxf(wmx[0], wmx[1]), fmaxf(wmx[2], wmx[3]));
  float sum = 0.f;
  #pragma unroll
  for (int i = 0; i < 8; ++i) {
    int t = i * 256 + tid;
    float v = (t < len) ? __expf(s[i] - mx) : 0.f;
    e[i] = v;
    sum += v;
  }
  #pragma unroll
  for (int off = 32; off; off >>= 1) sum += __shfl_xor(sum, off);
  if (lane == 0) wsum[w] = sum;
  __syncthreads();
  sum = wsum[0] + wsum[1] + wsum[2] + wsum[3];
  float inv = 1.f / sum;
  #pragma unroll
  for (int i = 0; i < 8; ++i) ali_out[n * T_LEN + i * 256 + tid] = e[i] * inv;
}

// ---------------- K3: ctx partials over T-chunks ----------------
__global__ void k_ctx(const float* __restrict__ ali, const float* __restrict__ enc,
                      float* __restrict__ part) {
  int b = blockIdx.x;                   // n*32 + tc
  int n = b >> 5, tc = b & 31;
  int tid = threadIdx.x;
  f32x4 acc = (f32x4){0.f, 0.f, 0.f, 0.f};
  const float* ep = enc + (size_t)(n * T_LEN + tc * 64) * ENC_D + tid * 4;
  const float* ap = ali + n * T_LEN + tc * 64;
  #pragma unroll 4
  for (int i = 0; i < 64; ++i) {
    float a = ap[i];
    f32x4 ev = *reinterpret_cast<const f32x4*>(ep + (size_t)i * ENC_D);
    acc += ev * a;
  }
  *reinterpret_cast<f32x4*>(&part[(size_t)b * ENC_D + tid * 4]) = acc;
}

// ---------------- K4: reduce ctx partials ----------------
__global__ void k_ctx_red(const float* __restrict__ part, float* __restrict__ ctx_out) {
  int g = blockIdx.x * 256 + threadIdx.x;
  int n = g >> 10, d = g & 1023;
  float s = 0.f;
  #pragma unroll 8
  for (int tc = 0; tc < 32; ++tc) s += part[(size_t)(n * 32 + tc) * ENC_D + d];
  ctx_out[g] = s;
}

extern "C" void kernel_launch(void* const* d_in, const int* in_sizes, int n_in,
                              void* d_out, int out_size, void* d_ws, size_t ws_size,
                              hipStream_t stream) {
  const float* enc      = (const float*)d_in[0];
  const int*   enc_len  = (const int*)d_in[1];
  const float* dec_prev = (const float*)d_in[2];
  const float* ali_prev = (const float*)d_in[3];
  const float* W_enc    = (const float*)d_in[4];
  const float* b_enc    = (const float*)d_in[5];
  const float* W_dec    = (const float*)d_in[6];
  const float* F_w      = (const float*)d_in[7];
  const float* F_b      = (const float*)d_in[8];
  const float* W_att    = (const float*)d_in[9];
  const float* w_vec    = (const float*)d_in[10];
  float* out = (float*)d_out;

  char* ws = (char*)d_ws;
  unsigned short* Wt2 = (unsigned short*)ws;       // 1,048,576 B (tiled)
  float* fout   = (float*)(ws + 1048576);          // 2,621,440 B
  float* dec_ws = (float*)(ws + 3670016);          //    65,536 B
  float* score  = (float*)(ws + 3735552);          //   524,288 B
  float* part   = (float*)(ws + 4259840);          // 4,194,304 B

  dim3 blk(256);
  hipLaunchKernelGGL(k_wt, dim3(16, 8), blk, 0, stream, W_enc, Wt2);
  hipLaunchKernelGGL(k_conv, dim3(2560), blk, 0, stream, ali_prev, F_w, F_b, fout);
  hipLaunchKernelGGL(k_dec, dim3(64), blk, 0, stream, dec_prev, W_dec, b_enc, dec_ws);
  hipLaunchKernelGGL(k_score, dim3(1024), blk, 0, stream, enc, Wt2, fout, dec_ws, W_att, w_vec, score);
  hipLaunchKernelGGL(k_softmax, dim3(32), blk, 0, stream, score, enc_len, out);
  hipLaunchKernelGGL(k_ctx, dim3(1024), blk, 0, stream, out, enc, part);
  hipLaunchKernelGGL(k_ctx_red, dim3(128), blk, 0, stream, part, out + 65536);
}

// Round 4
// 248.347 us; speedup vs baseline: 1.0927x; 1.0596x over previous
//
#include <hip/hip_runtime.h>

typedef __attribute__((ext_vector_type(4))) float f32x4;
typedef __attribute__((ext_vector_type(8))) short s16x8;
typedef __attribute__((ext_vector_type(8))) unsigned short u16x8;
typedef __attribute__((address_space(1))) unsigned int g_uint;
typedef __attribute__((address_space(3))) unsigned int lds_uint;

#define T_LEN 2048
#define ENC_D 1024
#define ATT_D 512
#define CONV_C 10

static __device__ __forceinline__ unsigned short f2bf(float f) {
  unsigned int u = __float_as_uint(f);
  u += 0x7FFFu + ((u >> 16) & 1u);
  return (unsigned short)(u >> 16);
}

static __device__ __forceinline__ void gload16(const void* g, void* l) {
  __builtin_amdgcn_global_load_lds((const g_uint*)g, (lds_uint*)l, 16, 0, 0);
}

// ---------------- K0a: Wt2 tiled: tile(h,kt)[a_local 256][k_local 32] bf16 ----------------
__global__ void k_wt(const float* __restrict__ W, unsigned short* __restrict__ Wt2) {
  __shared__ float tile[64][65];
  int k0 = blockIdx.x * 64, a0 = blockIdx.y * 64;
  int tid = threadIdx.x;
  int r = tid >> 2, cg = tid & 3;
  #pragma unroll
  for (int i = 0; i < 4; ++i) {
    f32x4 v = *reinterpret_cast<const f32x4*>(&W[(size_t)(k0 + r) * ATT_D + a0 + cg * 16 + i * 4]);
    tile[r][cg * 16 + i * 4 + 0] = v[0];
    tile[r][cg * 16 + i * 4 + 1] = v[1];
    tile[r][cg * 16 + i * 4 + 2] = v[2];
    tile[r][cg * 16 + i * 4 + 3] = v[3];
  }
  __syncthreads();
  int r2 = tid >> 2, kg = tid & 3;
  u16x8 o0, o1;
  #pragma unroll
  for (int j = 0; j < 8; ++j) o0[j] = f2bf(tile[kg * 16 + j][r2]);
  #pragma unroll
  for (int j = 0; j < 8; ++j) o1[j] = f2bf(tile[kg * 16 + 8 + j][r2]);
  int a = a0 + r2;            // 0..511
  int k = k0 + kg * 16;       // 0..1023, 16-aligned (within one 32-wide kt)
  size_t base = ((size_t)(a >> 8) * 32 + (k >> 5)) * 8192 + (size_t)(a & 255) * 32 + (k & 31);
  *reinterpret_cast<u16x8*>(&Wt2[base]) = o0;
  *reinterpret_cast<u16x8*>(&Wt2[base + 8]) = o1;
}

// ---------------- K0b: f_out[n][c][t] = conv129(ali_prev) + F_b ----------------
__global__ void k_conv(const float* __restrict__ ali, const float* __restrict__ Fw,
                       const float* __restrict__ Fb, float* __restrict__ fout) {
  int b = blockIdx.x;
  int tb = b & 7, nc = b >> 3;
  int c = nc % CONV_C, n = nc / CONV_C;
  __shared__ float sa[384];
  __shared__ float sw[129];
  int tid = threadIdx.x;
  int t0 = tb * 256;
  for (int i = tid; i < 384; i += 256) {
    int t = t0 - 64 + i;
    sa[i] = (t >= 0 && t < T_LEN) ? ali[n * T_LEN + t] : 0.f;
  }
  if (tid < 129) sw[tid] = Fw[c * 129 + tid];
  __syncthreads();
  float acc = Fb[c];
  #pragma unroll 8
  for (int k = 0; k < 129; ++k) acc += sw[k] * sa[tid + k];
  fout[(size_t)(n * CONV_C + c) * T_LEN + t0 + tid] = acc;
}

// ---------------- K0c: dec_ws[n][a] = dec_prev[n]@W_dec[:,a] + b_enc[a] ----------------
__global__ void k_dec(const float* __restrict__ dec_prev, const float* __restrict__ Wd,
                      const float* __restrict__ benc, float* __restrict__ dec_ws) {
  int b = blockIdx.x;
  int n = b >> 1, half = b & 1;
  int a = half * 256 + threadIdx.x;
  __shared__ float sd[1024];
  for (int i = threadIdx.x; i < 1024; i += 256) sd[i] = dec_prev[n * 1024 + i];
  __syncthreads();
  float acc = benc[a];
  #pragma unroll 8
  for (int d = 0; d < 1024; ++d) acc += sd[d] * Wd[(size_t)d * ATT_D + a];
  dec_ws[n * ATT_D + a] = acc;
}

// ---------------- K1: fused score GEMM (BM=128, BN=256-half, BK=32, 8 waves) ----------------
// ALL staging via global_load_lds: B bf16 (pre-tiled Wt2), A f32 with XOR-swizzled
// source (chunk ^= row&7, 16B chunks) so swizzled ds_read_b128 is bank-floor.
// A converted to bf16 at fragment load via v_cvt_pk_bf16_f32.
__global__ __launch_bounds__(512, 4) void k_score(
    const float* __restrict__ enc, const unsigned short* __restrict__ Wt2,
    const float* __restrict__ fout, const float* __restrict__ dec_ws,
    const float* __restrict__ W_att, const float* __restrict__ w_vec,
    float* __restrict__ score_ws) {
  __shared__ __align__(16) char smem[65536];
  char* B0c = smem;                 // [256][32] bf16 = 16384 B
  char* B1c = smem + 16384;
  char* A0c = smem + 32768;         // [128][32] f32 (16B-chunk swizzled) = 16384 B
  char* A1c = smem + 49152;

  int bid = blockIdx.x;             // nwg = 1024 (512 mt x 2 h), 1024 % 8 == 0
  int xcd = bid & 7, idx = bid >> 3;
  int mt = xcd * 64 + (idx >> 1);   // pair h-blocks of same mt on one XCD
  int h = idx & 1;

  int tid = threadIdx.x;
  int w = tid >> 6, lane = tid & 63;
  int l15 = lane & 15, q = lane >> 4;
  int wm = w >> 2, wn = w & 3;      // wave tile 64(M) x 64(N)
  int xr = l15 & 7;
  int c0off = ((2 * q) ^ xr) * 4;        // f32 offset of first 16B chunk
  int c1off = (((2 * q) | 1) ^ xr) * 4;  // second 16B chunk

  // A staging source (per-lane, inverse-swizzled): dest d=(i*512+tid)*16
  int arow = tid >> 3;
  int achk = (tid & 7) ^ (arow & 7);
  const float* srcA0 = enc + ((size_t)mt * 128 + arow) * ENC_D + achk * 4;
  const float* srcA1 = srcA0 + (size_t)64 * ENC_D;
  // B staging source (linear, pre-tiled)
  const unsigned short* srcB = Wt2 + ((size_t)h * 32) * 8192 + tid * 8;

  f32x4 acc[4][4];
  #pragma unroll
  for (int m = 0; m < 4; ++m)
    #pragma unroll
    for (int nf = 0; nf < 4; ++nf)
      acc[m][nf] = (f32x4){0.f, 0.f, 0.f, 0.f};

  auto stageB = [&](int kt, char* Bd) {
    const unsigned short* s = srcB + (size_t)kt * 8192;
    gload16(s, Bd + tid * 16);
    gload16(s + 4096, Bd + tid * 16 + 8192);
  };
  auto stageA = [&](int kt, char* Ad) {
    gload16(srcA0 + kt * 32, Ad + tid * 16);
    gload16(srcA1 + kt * 32, Ad + tid * 16 + 8192);
  };
  auto compute = [&](const char* Bc, const char* Ac) {
    const short* Bt = (const short*)Bc;
    const float* At = (const float*)Ac;
    s16x8 af[4];
    #pragma unroll
    for (int m = 0; m < 4; ++m) {
      const float* base = At + (wm * 64 + m * 16 + l15) * 32;
      f32x4 lo = *reinterpret_cast<const f32x4*>(base + c0off);
      f32x4 hi = *reinterpret_cast<const f32x4*>(base + c1off);
      union { s16x8 v; unsigned int u[4]; } pk;
      asm("v_cvt_pk_bf16_f32 %0, %1, %2" : "=v"(pk.u[0]) : "v"(lo[0]), "v"(lo[1]));
      asm("v_cvt_pk_bf16_f32 %0, %1, %2" : "=v"(pk.u[1]) : "v"(lo[2]), "v"(lo[3]));
      asm("v_cvt_pk_bf16_f32 %0, %1, %2" : "=v"(pk.u[2]) : "v"(hi[0]), "v"(hi[1]));
      asm("v_cvt_pk_bf16_f32 %0, %1, %2" : "=v"(pk.u[3]) : "v"(hi[2]), "v"(hi[3]));
      af[m] = pk.v;
    }
    #pragma unroll
    for (int i = 0; i < 4; ++i) {
      s16x8 bfr = *reinterpret_cast<const s16x8*>(&Bt[(wn * 64 + i * 16 + l15) * 32 + q * 8]);
      #pragma unroll
      for (int m = 0; m < 4; ++m)
        acc[m][i] = __builtin_amdgcn_mfma_f32_16x16x32_bf16(af[m], bfr, acc[m][i], 0, 0, 0);
    }
  };

  stageB(0, B0c);
  stageA(0, A0c);

  for (int kt = 0; kt < 32; kt += 2) {
    __syncthreads();                  // staging of kt complete (vmcnt drained)
    stageB(kt + 1, B1c);
    stageA(kt + 1, A1c);
    compute(B0c, A0c);
    __syncthreads();                  // staging of kt+1 complete
    if (kt + 2 < 32) {
      stageB(kt + 2, B0c);
      stageA(kt + 2, A0c);
    }
    compute(B1c, A1c);
  }
  __syncthreads();

  // ---- epilogue: att mix + dec + tanh + dot(w) + row-reduce ----
  float* f_lds = (float*)smem;               // [10][128] = 5120
  float* attw  = (float*)(smem + 5120);      // [256][10] = 10240
  float* d_lds = (float*)(smem + 15360);     // [256]
  float* w_lds = (float*)(smem + 16384);     // [256]
  float* red   = (float*)(smem + 17408);     // [8][64] = 2048

  int n = mt >> 4;
  int t0 = (mt & 15) * 128;

  for (int i = tid; i < 1280; i += 512) {
    int c = i >> 7, tt = i & 127;
    f_lds[c * 128 + tt] = fout[(size_t)(n * CONV_C + c) * T_LEN + t0 + tt];
  }
  for (int i = tid; i < 2560; i += 512) attw[i] = W_att[h * 2560 + i];
  if (tid < 256) {
    d_lds[tid] = dec_ws[n * ATT_D + h * 256 + tid];
    w_lds[tid] = w_vec[h * 256 + tid];
  }
  __syncthreads();

  #pragma unroll
  for (int m = 0; m < 4; ++m) {
    #pragma unroll
    for (int j = 0; j < 4; ++j) {
      int tt = wm * 64 + m * 16 + q * 4 + j;
      float s = 0.f;
      #pragma unroll
      for (int nf = 0; nf < 4; ++nf) {
        int cl = wn * 64 + nf * 16 + l15;
        float att = 0.f;
        #pragma unroll
        for (int c = 0; c < CONV_C; ++c) att += f_lds[c * 128 + tt] * attw[cl * CONV_C + c];
        float x = acc[m][nf][j] + d_lds[cl] + att;
        float e = __expf(2.f * x);
        float th = 1.f - 2.f / (e + 1.f);
        s += w_lds[cl] * th;
      }
      float v = s;
      v += __shfl_xor(v, 1);
      v += __shfl_xor(v, 2);
      v += __shfl_xor(v, 4);
      v += __shfl_xor(v, 8);
      if (l15 == 0) red[w * 64 + m * 16 + q * 4 + j] = v;
    }
  }
  __syncthreads();
  if (tid < 128) {
    int wm2 = tid >> 6, lr = tid & 63;
    float s = red[(wm2 * 4 + 0) * 64 + lr] + red[(wm2 * 4 + 1) * 64 + lr]
            + red[(wm2 * 4 + 2) * 64 + lr] + red[(wm2 * 4 + 3) * 64 + lr];
    score_ws[(size_t)h * 65536 + (size_t)mt * 128 + tid] = s;
  }
}

// ---------------- K2: masked softmax over T per row ----------------
__global__ void k_softmax(const float* __restrict__ score_ws, const int* __restrict__ enc_len,
                          float* __restrict__ ali_out) {
  __shared__ float wmx[4], wsum[4];
  int n = blockIdx.x, tid = threadIdx.x;
  int len = enc_len[n];
  int w = tid >> 6, lane = tid & 63;
  float s[8], e[8];
  float mx = -1e30f;
  #pragma unroll
  for (int i = 0; i < 8; ++i) {
    int t = i * 256 + tid;
    float v = score_ws[n * T_LEN + t] + score_ws[65536 + n * T_LEN + t];
    s[i] = v;
    if (t < len) mx = fmaxf(mx, v);
  }
  #pragma unroll
  for (int off = 32; off; off >>= 1) mx = fmaxf(mx, __shfl_xor(mx, off));
  if (lane == 0) wmx[w] = mx;
  __syncthreads();
  mx = fmaxf(fmaxf(wmx[0], wmx[1]), fmaxf(wmx[2], wmx[3]));
  float sum = 0.f;
  #pragma unroll
  for (int i = 0; i < 8; ++i) {
    int t = i * 256 + tid;
    float v = (t < len) ? __expf(s[i] - mx) : 0.f;
    e[i] = v;
    sum += v;
  }
  #pragma unroll
  for (int off = 32; off; off >>= 1) sum += __shfl_xor(sum, off);
  if (lane == 0) wsum[w] = sum;
  __syncthreads();
  sum = wsum[0] + wsum[1] + wsum[2] + wsum[3];
  float inv = 1.f / sum;
  #pragma unroll
  for (int i = 0; i < 8; ++i) ali_out[n * T_LEN + i * 256 + tid] = e[i] * inv;
}

// ---------------- K3: ctx partials over T-chunks ----------------
__global__ void k_ctx(const float* __restrict__ ali, const float* __restrict__ enc,
                      float* __restrict__ part) {
  int b = blockIdx.x;                   // n*32 + tc
  int n = b >> 5, tc = b & 31;
  int tid = threadIdx.x;
  f32x4 acc = (f32x4){0.f, 0.f, 0.f, 0.f};
  const float* ep = enc + (size_t)(n * T_LEN + tc * 64) * ENC_D + tid * 4;
  const float* ap = ali + n * T_LEN + tc * 64;
  #pragma unroll 4
  for (int i = 0; i < 64; ++i) {
    float a = ap[i];
    f32x4 ev = *reinterpret_cast<const f32x4*>(ep + (size_t)i * ENC_D);
    acc += ev * a;
  }
  *reinterpret_cast<f32x4*>(&part[(size_t)b * ENC_D + tid * 4]) = acc;
}

// ---------------- K4: reduce ctx partials ----------------
__global__ void k_ctx_red(const float* __restrict__ part, float* __restrict__ ctx_out) {
  int g = blockIdx.x * 256 + threadIdx.x;
  int n = g >> 10, d = g & 1023;
  float s = 0.f;
  #pragma unroll 8
  for (int tc = 0; tc < 32; ++tc) s += part[(size_t)(n * 32 + tc) * ENC_D + d];
  ctx_out[g] = s;
}

extern "C" void kernel_launch(void* const* d_in, const int* in_sizes, int n_in,
                              void* d_out, int out_size, void* d_ws, size_t ws_size,
                              hipStream_t stream) {
  const float* enc      = (const float*)d_in[0];
  const int*   enc_len  = (const int*)d_in[1];
  const float* dec_prev = (const float*)d_in[2];
  const float* ali_prev = (const float*)d_in[3];
  const float* W_enc    = (const float*)d_in[4];
  const float* b_enc    = (const float*)d_in[5];
  const float* W_dec    = (const float*)d_in[6];
  const float* F_w      = (const float*)d_in[7];
  const float* F_b      = (const float*)d_in[8];
  const float* W_att    = (const float*)d_in[9];
  const float* w_vec    = (const float*)d_in[10];
  float* out = (float*)d_out;

  char* ws = (char*)d_ws;
  unsigned short* Wt2 = (unsigned short*)ws;       // 1,048,576 B (tiled)
  float* fout   = (float*)(ws + 1048576);          // 2,621,440 B
  float* dec_ws = (float*)(ws + 3670016);          //    65,536 B
  float* score  = (float*)(ws + 3735552);          //   524,288 B
  float* part   = (float*)(ws + 4259840);          // 4,194,304 B

  hipLaunchKernelGGL(k_wt, dim3(16, 8), dim3(256), 0, stream, W_enc, Wt2);
  hipLaunchKernelGGL(k_conv, dim3(2560), dim3(256), 0, stream, ali_prev, F_w, F_b, fout);
  hipLaunchKernelGGL(k_dec, dim3(64), dim3(256), 0, stream, dec_prev, W_dec, b_enc, dec_ws);
  hipLaunchKernelGGL(k_score, dim3(1024), dim3(512), 0, stream, enc, Wt2, fout, dec_ws, W_att, w_vec, score);
  hipLaunchKernelGGL(k_softmax, dim3(32), dim3(256), 0, stream, score, enc_len, out);
  hipLaunchKernelGGL(k_ctx, dim3(1024), dim3(256), 0, stream, out, enc, part);
  hipLaunchKernelGGL(k_ctx_red, dim3(128), dim3(256), 0, stream, part, out + 65536);
}

// Round 5
// 237.652 us; speedup vs baseline: 1.1419x; 1.0450x over previous
//
#include <hip/hip_runtime.h>

typedef __attribute__((ext_vector_type(4))) float f32x4;
typedef __attribute__((ext_vector_type(8))) short s16x8;
typedef __attribute__((ext_vector_type(8))) unsigned short u16x8;
typedef __attribute__((address_space(1))) unsigned int g_uint;
typedef __attribute__((address_space(3))) unsigned int lds_uint;

#define T_LEN 2048
#define ENC_D 1024
#define ATT_D 512
#define CONV_C 10

static __device__ __forceinline__ unsigned short f2bf(float f) {
  unsigned int u = __float_as_uint(f);
  u += 0x7FFFu + ((u >> 16) & 1u);
  return (unsigned short)(u >> 16);
}

static __device__ __forceinline__ void gload16(const void* g, void* l) {
  __builtin_amdgcn_global_load_lds((const g_uint*)g, (lds_uint*)l, 16, 0, 0);
}

// ---------------- K0a: Wt2 tiled: tile(h,kt)[a_local 256][k_local 32] bf16 ----------------
__global__ void k_wt(const float* __restrict__ W, unsigned short* __restrict__ Wt2) {
  __shared__ float tile[64][65];
  int k0 = blockIdx.x * 64, a0 = blockIdx.y * 64;
  int tid = threadIdx.x;
  int r = tid >> 2, cg = tid & 3;
  #pragma unroll
  for (int i = 0; i < 4; ++i) {
    f32x4 v = *reinterpret_cast<const f32x4*>(&W[(size_t)(k0 + r) * ATT_D + a0 + cg * 16 + i * 4]);
    tile[r][cg * 16 + i * 4 + 0] = v[0];
    tile[r][cg * 16 + i * 4 + 1] = v[1];
    tile[r][cg * 16 + i * 4 + 2] = v[2];
    tile[r][cg * 16 + i * 4 + 3] = v[3];
  }
  __syncthreads();
  int r2 = tid >> 2, kg = tid & 3;
  u16x8 o0, o1;
  #pragma unroll
  for (int j = 0; j < 8; ++j) o0[j] = f2bf(tile[kg * 16 + j][r2]);
  #pragma unroll
  for (int j = 0; j < 8; ++j) o1[j] = f2bf(tile[kg * 16 + 8 + j][r2]);
  int a = a0 + r2;            // 0..511
  int k = k0 + kg * 16;       // 0..1023, 16-aligned (within one 32-wide kt)
  size_t base = ((size_t)(a >> 8) * 32 + (k >> 5)) * 8192 + (size_t)(a & 255) * 32 + (k & 31);
  *reinterpret_cast<u16x8*>(&Wt2[base]) = o0;
  *reinterpret_cast<u16x8*>(&Wt2[base + 8]) = o1;
}

// ---------------- K0b: f_out[n][c][t] = conv129(ali_prev) + F_b ----------------
__global__ void k_conv(const float* __restrict__ ali, const float* __restrict__ Fw,
                       const float* __restrict__ Fb, float* __restrict__ fout) {
  int b = blockIdx.x;
  int tb = b & 7, nc = b >> 3;
  int c = nc % CONV_C, n = nc / CONV_C;
  __shared__ float sa[384];
  __shared__ float sw[129];
  int tid = threadIdx.x;
  int t0 = tb * 256;
  for (int i = tid; i < 384; i += 256) {
    int t = t0 - 64 + i;
    sa[i] = (t >= 0 && t < T_LEN) ? ali[n * T_LEN + t] : 0.f;
  }
  if (tid < 129) sw[tid] = Fw[c * 129 + tid];
  __syncthreads();
  float acc = Fb[c];
  #pragma unroll 8
  for (int k = 0; k < 129; ++k) acc += sw[k] * sa[tid + k];
  fout[(size_t)(n * CONV_C + c) * T_LEN + t0 + tid] = acc;
}

// ---------------- K0c: dec_ws[n][a] = dec_prev[n]@W_dec[:,a] + b_enc[a] ----------------
__global__ void k_dec(const float* __restrict__ dec_prev, const float* __restrict__ Wd,
                      const float* __restrict__ benc, float* __restrict__ dec_ws) {
  int b = blockIdx.x;
  int n = b >> 1, half = b & 1;
  int a = half * 256 + threadIdx.x;
  __shared__ float sd[1024];
  for (int i = threadIdx.x; i < 1024; i += 256) sd[i] = dec_prev[n * 1024 + i];
  __syncthreads();
  float acc = benc[a];
  #pragma unroll 8
  for (int d = 0; d < 1024; ++d) acc += sd[d] * Wd[(size_t)d * ATT_D + a];
  dec_ws[n * ATT_D + a] = acc;
}

// ---------------- K1: fused score GEMM (BM=128, BN=256-half, BK=32, 8 waves) ----------------
// Counted-vmcnt pipeline: 3 LDS buffers, 1 barrier/K-step, loads span barriers.
// A: global f32 -> regs (2-deep) -> cvt_pk bf16 -> ds_write_b128.
// B: global_load_lds from pre-tiled bf16 Wt2.
__global__ __launch_bounds__(512, 4) void k_score(
    const float* __restrict__ enc, const unsigned short* __restrict__ Wt2,
    const float* __restrict__ fout, const float* __restrict__ dec_ws,
    const float* __restrict__ W_att, const float* __restrict__ w_vec,
    float* __restrict__ score_ws) {
  __shared__ __align__(16) char smem[73728];   // 3 x (B 16384 + A 8192)

  int bid = blockIdx.x;             // nwg = 1024 (512 mt x 2 h), 1024 % 8 == 0
  int xcd = bid & 7, idx = bid >> 3;
  int mt = xcd * 64 + (idx >> 1);   // pair h-blocks of same mt on one XCD (A L2 reuse)
  int h = idx & 1;

  int tid = threadIdx.x;
  int w = tid >> 6, lane = tid & 63;
  int l15 = lane & 15, q = lane >> 4;
  int wm = w >> 2, wn = w & 3;      // wave tile 64(M) x 64(N)

  // A staging: thread -> (row = tid>>2, 8 f32 at col (tid&3)*8)
  int arow = tid >> 2, aq = tid & 3;
  const float* Asrc = enc + ((size_t)mt * 128 + arow) * ENC_D + aq * 8;
  // B staging: linear copy of pre-tiled 16KB tile
  const unsigned short* Bsrc = Wt2 + (size_t)h * 32 * 8192 + tid * 8;

  f32x4 acc[4][4];
  #pragma unroll
  for (int m = 0; m < 4; ++m)
    #pragma unroll
    for (int nf = 0; nf < 4; ++nf)
      acc[m][nf] = (f32x4){0.f, 0.f, 0.f, 0.f};

  f32x4 ra0, ra1, rb0, rb1;   // two A prefetch slots (static names, rule #20)

  auto issueA = [&](int kt, f32x4& x0, f32x4& x1) {
    const float* p = Asrc + kt * 32;
    x0 = *reinterpret_cast<const f32x4*>(p);
    x1 = *reinterpret_cast<const f32x4*>(p + 4);
  };
  auto issueB = [&](int kt) {
    const unsigned short* s = Bsrc + (size_t)kt * 8192;
    char* Bd = smem + (kt % 3) * 24576;
    gload16(s, Bd + tid * 16);
    gload16(s + 4096, Bd + tid * 16 + 8192);
  };
  auto writeA = [&](int kt, f32x4& x0, f32x4& x1) {
    char* Ad = smem + (kt % 3) * 24576 + 16384;
    union { u16x8 v; unsigned int u[4]; } pk;
    asm("v_cvt_pk_bf16_f32 %0, %1, %2" : "=v"(pk.u[0]) : "v"(x0[0]), "v"(x0[1]));
    asm("v_cvt_pk_bf16_f32 %0, %1, %2" : "=v"(pk.u[1]) : "v"(x0[2]), "v"(x0[3]));
    asm("v_cvt_pk_bf16_f32 %0, %1, %2" : "=v"(pk.u[2]) : "v"(x1[0]), "v"(x1[1]));
    asm("v_cvt_pk_bf16_f32 %0, %1, %2" : "=v"(pk.u[3]) : "v"(x1[2]), "v"(x1[3]));
    *reinterpret_cast<u16x8*>(Ad + arow * 64 + aq * 16) = pk.v;
  };
  auto compute = [&](int kt) {
    const char* buf = smem + (kt % 3) * 24576;
    const short* Bt = (const short*)buf;
    const short* At = (const short*)(buf + 16384);
    s16x8 af[4];
    #pragma unroll
    for (int m = 0; m < 4; ++m)
      af[m] = *reinterpret_cast<const s16x8*>(&At[(wm * 64 + m * 16 + l15) * 32 + q * 8]);
    #pragma unroll
    for (int i = 0; i < 4; ++i) {
      s16x8 bfr = *reinterpret_cast<const s16x8*>(&Bt[(wn * 64 + i * 16 + l15) * 32 + q * 8]);
      #pragma unroll
      for (int m = 0; m < 4; ++m)
        acc[m][i] = __builtin_amdgcn_mfma_f32_16x16x32_bf16(af[m], bfr, acc[m][i], 0, 0, 0);
    }
  };

  // ---- prologue ----
  issueA(0, ra0, ra1);
  issueA(1, rb0, rb1);
  issueB(0);
  asm volatile("s_waitcnt vmcnt(4)" ::: "memory");   // retire A(0)
  __builtin_amdgcn_sched_barrier(0);
  writeA(0, ra0, ra1);

  // ---- main loop: 1 barrier per K-step, counted vmcnt ----
  for (int k = 0; k < 32; k += 2) {
    // even step k
    if (k + 2 < 32) issueA(k + 2, ra0, ra1);
    issueB(k + 1);
    asm volatile("s_waitcnt vmcnt(4) lgkmcnt(0)" ::: "memory");  // retire B(k), A(k+1)
    __builtin_amdgcn_sched_barrier(0);
    __builtin_amdgcn_s_barrier();
    compute(k);
    writeA(k + 1, rb0, rb1);
    // odd step k+1
    if (k + 3 < 32) issueA(k + 3, rb0, rb1);
    if (k + 2 < 32) {
      issueB(k + 2);
      asm volatile("s_waitcnt vmcnt(4) lgkmcnt(0)" ::: "memory");
    } else {
      asm volatile("s_waitcnt vmcnt(0) lgkmcnt(0)" ::: "memory");
    }
    __builtin_amdgcn_sched_barrier(0);
    __builtin_amdgcn_s_barrier();
    compute(k + 1);
    if (k + 2 < 32) writeA(k + 2, ra0, ra1);
  }
  __syncthreads();

  // ---- epilogue: att mix + dec + tanh + dot(w) + row-reduce ----
  float* f_lds = (float*)smem;               // [10][128] = 5120
  float* attw  = (float*)(smem + 5120);      // [256][10] = 10240
  float* d_lds = (float*)(smem + 15360);     // [256]
  float* w_lds = (float*)(smem + 16384);     // [256]
  float* red   = (float*)(smem + 17408);     // [8][64] = 2048

  int n = mt >> 4;
  int t0 = (mt & 15) * 128;

  for (int i = tid; i < 1280; i += 512) {
    int c = i >> 7, tt = i & 127;
    f_lds[c * 128 + tt] = fout[(size_t)(n * CONV_C + c) * T_LEN + t0 + tt];
  }
  for (int i = tid; i < 2560; i += 512) attw[i] = W_att[h * 2560 + i];
  if (tid < 256) {
    d_lds[tid] = dec_ws[n * ATT_D + h * 256 + tid];
    w_lds[tid] = w_vec[h * 256 + tid];
  }
  __syncthreads();

  #pragma unroll
  for (int m = 0; m < 4; ++m) {
    #pragma unroll
    for (int j = 0; j < 4; ++j) {
      int tt = wm * 64 + m * 16 + q * 4 + j;
      float s = 0.f;
      #pragma unroll
      for (int nf = 0; nf < 4; ++nf) {
        int cl = wn * 64 + nf * 16 + l15;
        float att = 0.f;
        #pragma unroll
        for (int c = 0; c < CONV_C; ++c) att += f_lds[c * 128 + tt] * attw[cl * CONV_C + c];
        float x = acc[m][nf][j] + d_lds[cl] + att;
        float e = __expf(2.f * x);
        float th = 1.f - 2.f / (e + 1.f);
        s += w_lds[cl] * th;
      }
      float v = s;
      v += __shfl_xor(v, 1);
      v += __shfl_xor(v, 2);
      v += __shfl_xor(v, 4);
      v += __shfl_xor(v, 8);
      if (l15 == 0) red[w * 64 + m * 16 + q * 4 + j] = v;
    }
  }
  __syncthreads();
  if (tid < 128) {
    int wm2 = tid >> 6, lr = tid & 63;
    float s = red[(wm2 * 4 + 0) * 64 + lr] + red[(wm2 * 4 + 1) * 64 + lr]
            + red[(wm2 * 4 + 2) * 64 + lr] + red[(wm2 * 4 + 3) * 64 + lr];
    score_ws[(size_t)h * 65536 + (size_t)mt * 128 + tid] = s;
  }
}

// ---------------- K2: masked softmax over T per row ----------------
__global__ void k_softmax(const float* __restrict__ score_ws, const int* __restrict__ enc_len,
                          float* __restrict__ ali_out) {
  __shared__ float wmx[4], wsum[4];
  int n = blockIdx.x, tid = threadIdx.x;
  int len = enc_len[n];
  int w = tid >> 6, lane = tid & 63;
  float s[8], e[8];
  float mx = -1e30f;
  #pragma unroll
  for (int i = 0; i < 8; ++i) {
    int t = i * 256 + tid;
    float v = score_ws[n * T_LEN + t] + score_ws[65536 + n * T_LEN + t];
    s[i] = v;
    if (t < len) mx = fmaxf(mx, v);
  }
  #pragma unroll
  for (int off = 32; off; off >>= 1) mx = fmaxf(mx, __shfl_xor(mx, off));
  if (lane == 0) wmx[w] = mx;
  __syncthreads();
  mx = fmaxf(fmaxf(wmx[0], wmx[1]), fmaxf(wmx[2], wmx[3]));
  float sum = 0.f;
  #pragma unroll
  for (int i = 0; i < 8; ++i) {
    int t = i * 256 + tid;
    float v = (t < len) ? __expf(s[i] - mx) : 0.f;
    e[i] = v;
    sum += v;
  }
  #pragma unroll
  for (int off = 32; off; off >>= 1) sum += __shfl_xor(sum, off);
  if (lane == 0) wsum[w] = sum;
  __syncthreads();
  sum = wsum[0] + wsum[1] + wsum[2] + wsum[3];
  float inv = 1.f / sum;
  #pragma unroll
  for (int i = 0; i < 8; ++i) ali_out[n * T_LEN + i * 256 + tid] = e[i] * inv;
}

// ---------------- K3: ctx partials over T-chunks ----------------
__global__ void k_ctx(const float* __restrict__ ali, const float* __restrict__ enc,
                      float* __restrict__ part) {
  int b = blockIdx.x;                   // n*32 + tc
  int n = b >> 5, tc = b & 31;
  int tid = threadIdx.x;
  f32x4 acc = (f32x4){0.f, 0.f, 0.f, 0.f};
  const float* ep = enc + (size_t)(n * T_LEN + tc * 64) * ENC_D + tid * 4;
  const float* ap = ali + n * T_LEN + tc * 64;
  #pragma unroll 4
  for (int i = 0; i < 64; ++i) {
    float a = ap[i];
    f32x4 ev = *reinterpret_cast<const f32x4*>(ep + (size_t)i * ENC_D);
    acc += ev * a;
  }
  *reinterpret_cast<f32x4*>(&part[(size_t)b * ENC_D + tid * 4]) = acc;
}

// ---------------- K4: reduce ctx partials ----------------
__global__ void k_ctx_red(const float* __restrict__ part, float* __restrict__ ctx_out) {
  int g = blockIdx.x * 256 + threadIdx.x;
  int n = g >> 10, d = g & 1023;
  float s = 0.f;
  #pragma unroll 8
  for (int tc = 0; tc < 32; ++tc) s += part[(size_t)(n * 32 + tc) * ENC_D + d];
  ctx_out[g] = s;
}

extern "C" void kernel_launch(void* const* d_in, const int* in_sizes, int n_in,
                              void* d_out, int out_size, void* d_ws, size_t ws_size,
                              hipStream_t stream) {
  const float* enc      = (const float*)d_in[0];
  const int*   enc_len  = (const int*)d_in[1];
  const float* dec_prev = (const float*)d_in[2];
  const float* ali_prev = (const float*)d_in[3];
  const float* W_enc    = (const float*)d_in[4];
  const float* b_enc    = (const float*)d_in[5];
  const float* W_dec    = (const float*)d_in[6];
  const float* F_w      = (const float*)d_in[7];
  const float* F_b      = (const float*)d_in[8];
  const float* W_att    = (const float*)d_in[9];
  const float* w_vec    = (const float*)d_in[10];
  float* out = (float*)d_out;

  char* ws = (char*)d_ws;
  unsigned short* Wt2 = (unsigned short*)ws;       // 1,048,576 B (tiled)
  float* fout   = (float*)(ws + 1048576);          // 2,621,440 B
  float* dec_ws = (float*)(ws + 3670016);          //    65,536 B
  float* score  = (float*)(ws + 3735552);          //   524,288 B
  float* part   = (float*)(ws + 4259840);          // 4,194,304 B

  hipLaunchKernelGGL(k_wt, dim3(16, 8), dim3(256), 0, stream, W_enc, Wt2);
  hipLaunchKernelGGL(k_conv, dim3(2560), dim3(256), 0, stream, ali_prev, F_w, F_b, fout);
  hipLaunchKernelGGL(k_dec, dim3(64), dim3(256), 0, stream, dec_prev, W_dec, b_enc, dec_ws);
  hipLaunchKernelGGL(k_score, dim3(1024), dim3(512), 0, stream, enc, Wt2, fout, dec_ws, W_att, w_vec, score);
  hipLaunchKernelGGL(k_softmax, dim3(32), dim3(256), 0, stream, score, enc_len, out);
  hipLaunchKernelGGL(k_ctx, dim3(1024), dim3(256), 0, stream, out, enc, part);
  hipLaunchKernelGGL(k_ctx_red, dim3(128), dim3(256), 0, stream, part, out + 65536);
}